// Round 1
// baseline (1446.188 us; speedup 1.0000x reference)
//
#include <hip/hip_runtime.h>

#define KC 4096
#define DD 256
#define BB 32768
#define P_BETA 0.25f
#define P_DECAY 0.99f
#define P_EPS 1e-5f

// ---------------------------------------------------------------------------
// Kernel 1: c_norm[k] = sum_d codebook[k][d]^2.  One wave per code row.
// ---------------------------------------------------------------------------
__global__ __launch_bounds__(256) void cnorm_kernel(const float* __restrict__ cb,
                                                    float* __restrict__ cn) {
    int lane = threadIdx.x & 63;
    int k = blockIdx.x * 4 + (threadIdx.x >> 6);
    float4 v = ((const float4*)(cb + (size_t)k * DD))[lane];  // 64 lanes * 4 = 256
    float s = v.x * v.x + v.y * v.y + v.z * v.z + v.w * v.w;
#pragma unroll
    for (int m = 32; m; m >>= 1) s += __shfl_xor(s, m);
    if (lane == 0) cn[k] = s;
}

// ---------------------------------------------------------------------------
// Kernel 2: distance argmin.  score[i,k] = c_norm[k] - 2*dot(z_i, c_k)
// Tiled f32 GEMM with argmin epilogue.
// BM=64 rows/block, K looped in BN=128 chunks, D in BK=64 chunks.
// 256 threads = 16x16; each thread: 4 rows x 8 cols register tile.
// LDS layout transposed [d][row]/[d][col] so fragment reads are float4,
// conflict-free (16 distinct addresses spanning 64 consecutive floats).
// ---------------------------------------------------------------------------
#define BM 64
#define BN 128
#define BK 64

__global__ __launch_bounds__(256) void argmin_kernel(const float* __restrict__ z,
                                                     const float* __restrict__ cb,
                                                     const float* __restrict__ cn,
                                                     int* __restrict__ idx_i,
                                                     float* __restrict__ idx_f) {
    __shared__ float zs[BK][BM];  // 16 KB, [d][row]
    __shared__ float cs[BK][BN];  // 32 KB, [d][col]

    const int tid = threadIdx.x;
    const int tx = tid & 15;   // col group
    const int ty = tid >> 4;   // row group (0..15) -> rows 4*ty..4*ty+3
    const int row0 = blockIdx.x * BM;

    float best[4];
    int bidx[4];
#pragma unroll
    for (int r = 0; r < 4; ++r) { best[r] = 3.4e38f; bidx[r] = 0; }

    for (int kc = 0; kc < KC; kc += BN) {
        float acc[4][8];
#pragma unroll
        for (int r = 0; r < 4; ++r)
#pragma unroll
            for (int c = 0; c < 8; ++c) acc[r][c] = 0.0f;

        for (int dc = 0; dc < DD; dc += BK) {
            // stage zs: thread handles row r = tid/4, d-quarter dq = tid%4
            {
                const int r = tid >> 2, dq = tid & 3;
                const float* gp = z + (size_t)(row0 + r) * DD + dc + dq * 16;
#pragma unroll
                for (int j = 0; j < 4; ++j) {
                    float4 v = ((const float4*)gp)[j];
                    int d = dq * 16 + j * 4;
                    zs[d + 0][r] = v.x; zs[d + 1][r] = v.y;
                    zs[d + 2][r] = v.z; zs[d + 3][r] = v.w;
                }
            }
            // stage cs: thread handles col c = tid/2, d-half dq = tid%2
            {
                const int c = tid >> 1, dq = tid & 1;
                const float* gp = cb + (size_t)(kc + c) * DD + dc + dq * 32;
#pragma unroll
                for (int j = 0; j < 8; ++j) {
                    float4 v = ((const float4*)gp)[j];
                    int d = dq * 32 + j * 4;
                    cs[d + 0][c] = v.x; cs[d + 1][c] = v.y;
                    cs[d + 2][c] = v.z; cs[d + 3][c] = v.w;
                }
            }
            __syncthreads();

#pragma unroll 8
            for (int d = 0; d < BK; ++d) {
                float4 a  = *(const float4*)&zs[d][ty * 4];
                float4 b0 = *(const float4*)&cs[d][tx * 4];
                float4 b1 = *(const float4*)&cs[d][64 + tx * 4];
                float av[4] = {a.x, a.y, a.z, a.w};
                float bv[8] = {b0.x, b0.y, b0.z, b0.w, b1.x, b1.y, b1.z, b1.w};
#pragma unroll
                for (int r = 0; r < 4; ++r)
#pragma unroll
                    for (int c = 0; c < 8; ++c)
                        acc[r][c] = fmaf(av[r], bv[c], acc[r][c]);
            }
            __syncthreads();
        }

        // fold this K-chunk into the running argmin
#pragma unroll
        for (int c = 0; c < 8; ++c) {
            int col = kc + ((c < 4) ? (tx * 4 + c) : (64 + tx * 4 + (c - 4)));
            float cnv = cn[col];
#pragma unroll
            for (int r = 0; r < 4; ++r) {
                float dist = fmaf(-2.0f, acc[r][c], cnv);
                if (dist < best[r]) { best[r] = dist; bidx[r] = col; }
            }
        }
    }

    // reduce across the 16 tx lanes (same rows); lanes = (ty%4)*16 + tx in wave
#pragma unroll
    for (int m = 1; m < 16; m <<= 1) {
#pragma unroll
        for (int r = 0; r < 4; ++r) {
            float ov = __shfl_xor(best[r], m);
            int oi = __shfl_xor(bidx[r], m);
            if (ov < best[r] || (ov == best[r] && oi < bidx[r])) {
                best[r] = ov; bidx[r] = oi;
            }
        }
    }
    if (tx == 0) {
#pragma unroll
        for (int r = 0; r < 4; ++r) {
            int row = row0 + ty * 4 + r;
            idx_i[row] = bidx[r];
            idx_f[row] = (float)bidx[r];
        }
    }
}

// ---------------------------------------------------------------------------
// Kernel 3: per-row scatter: z_q gather, commit partial, dw/counts atomics.
// One block (256 threads) per input row.
// ---------------------------------------------------------------------------
__global__ __launch_bounds__(256) void scatter_kernel(const float* __restrict__ z,
                                                      const float* __restrict__ cb,
                                                      const int* __restrict__ idx_i,
                                                      float* __restrict__ zq_out,
                                                      float* __restrict__ dw,
                                                      float* __restrict__ counts,
                                                      float* __restrict__ commit_ws) {
    const int i = blockIdx.x;
    const int t = threadIdx.x;
    const int k = idx_i[i];
    const float zv = z[(size_t)i * DD + t];
    const float cv = cb[(size_t)k * DD + t];
    zq_out[(size_t)i * DD + t] = cv;

    float d = zv - cv;
    float s = d * d;
#pragma unroll
    for (int m = 32; m; m >>= 1) s += __shfl_xor(s, m);
    __shared__ float ls[4];
    if ((t & 63) == 0) ls[t >> 6] = s;
    __syncthreads();

    atomicAdd(&dw[(size_t)k * DD + t], zv);
    if (t == 0) {
        atomicAdd(commit_ws, ls[0] + ls[1] + ls[2] + ls[3]);
        atomicAdd(&counts[k], 1.0f);
    }
}

// ---------------------------------------------------------------------------
// Kernel 4: new_cluster[k] = ema_cs*DECAY + counts*(1-DECAY); n = sum.
// ---------------------------------------------------------------------------
__global__ __launch_bounds__(256) void cluster_kernel(const float* __restrict__ ema_cs,
                                                      const float* __restrict__ counts,
                                                      float* __restrict__ out_cluster,
                                                      float* __restrict__ n_ws) {
    const int k = blockIdx.x * 256 + threadIdx.x;
    float nc = ema_cs[k] * P_DECAY + counts[k] * (1.0f - P_DECAY);
    out_cluster[k] = nc;
    float s = nc;
#pragma unroll
    for (int m = 32; m; m >>= 1) s += __shfl_xor(s, m);
    __shared__ float ls[4];
    if ((threadIdx.x & 63) == 0) ls[threadIdx.x >> 6] = s;
    __syncthreads();
    if (threadIdx.x == 0) atomicAdd(n_ws, ls[0] + ls[1] + ls[2] + ls[3]);
}

// ---------------------------------------------------------------------------
// Kernel 5: new_ema_weight, new_codebook, commit.
// ---------------------------------------------------------------------------
__global__ __launch_bounds__(256) void finalize_kernel(const float* __restrict__ ema_w,
                                                       const float* __restrict__ dw,
                                                       const float* __restrict__ out_cluster,
                                                       const float* __restrict__ n_ws,
                                                       const float* __restrict__ commit_ws,
                                                       float* __restrict__ out_ema_w,
                                                       float* __restrict__ out_codebook,
                                                       float* __restrict__ out_commit) {
    const size_t id = (size_t)blockIdx.x * 256 + threadIdx.x;
    const int k = (int)(id >> 8);  // D = 256
    const float n = *n_ws;
    float nw = ema_w[id] * P_DECAY + dw[id] * (1.0f - P_DECAY);
    out_ema_w[id] = nw;
    float cl = out_cluster[k];
    float csz = (cl + P_EPS) / (n + (float)KC * P_EPS) * n;
    out_codebook[id] = nw / csz;
    if (id == 0) *out_commit = P_BETA * (*commit_ws) / (float)((size_t)BB * DD);
}

// ---------------------------------------------------------------------------
extern "C" void kernel_launch(void* const* d_in, const int* in_sizes, int n_in,
                              void* d_out, int out_size, void* d_ws, size_t ws_size,
                              hipStream_t stream) {
    const float* z      = (const float*)d_in[0];  // [B,D]
    const float* cb     = (const float*)d_in[1];  // [K,D]
    const float* ema_cs = (const float*)d_in[2];  // [K]
    const float* ema_w  = (const float*)d_in[3];  // [K,D]

    // workspace layout
    float* ws        = (float*)d_ws;
    float* counts    = ws;                         // K
    float* dw        = counts + KC;                // K*D
    float* c_norm    = dw + (size_t)KC * DD;       // K
    int*   idx_i     = (int*)(c_norm + KC);        // B
    float* commit_ws = (float*)(idx_i + BB);       // 1
    float* n_ws      = commit_ws + 1;              // 1

    // output layout (flat, return order)
    float* out         = (float*)d_out;
    float* o_zq        = out;                            // B*D
    float* o_idx       = o_zq + (size_t)BB * DD;         // B
    float* o_commit    = o_idx + BB;                     // 1
    float* o_codebook  = o_commit + 1;                   // K*D
    float* o_cluster   = o_codebook + (size_t)KC * DD;   // K
    float* o_emaw      = o_cluster + KC;                 // K*D

    // zero the accumulated regions (ws is re-poisoned 0xAA before every call)
    hipMemsetAsync(counts, 0, (size_t)(KC + (size_t)KC * DD) * sizeof(float), stream);
    hipMemsetAsync(commit_ws, 0, 2 * sizeof(float), stream);

    cnorm_kernel<<<KC / 4, 256, 0, stream>>>(cb, c_norm);
    argmin_kernel<<<BB / BM, 256, 0, stream>>>(z, cb, c_norm, idx_i, o_idx);
    scatter_kernel<<<BB, 256, 0, stream>>>(z, cb, idx_i, o_zq, dw, counts, commit_ws);
    cluster_kernel<<<KC / 256, 256, 0, stream>>>(ema_cs, counts, o_cluster, n_ws);
    finalize_kernel<<<(KC * DD) / 256, 256, 0, stream>>>(ema_w, dw, o_cluster, n_ws,
                                                         commit_ws, o_emaw, o_codebook,
                                                         o_commit);
    (void)in_sizes; (void)n_in; (void)out_size; (void)ws_size;
}

// Round 2
// 630.879 us; speedup vs baseline: 2.2923x; 2.2923x over previous
//
#include <hip/hip_runtime.h>

#define KC 4096
#define DD 256
#define BB 32768
#define D2 768
#define P_BETA 0.25f
#define P_DECAY 0.99f
#define P_EPS 1e-5f
#define TAU 0.1f

typedef __attribute__((ext_vector_type(8))) short bf16x8;
typedef __attribute__((ext_vector_type(4))) float f32x4;

static __device__ __forceinline__ unsigned short f2bf(float f) {
    unsigned int u = __float_as_uint(f);
    unsigned int r = (u + 0x7fffu + ((u >> 16) & 1u)) >> 16;
    return (unsigned short)r;
}
static __device__ __forceinline__ float bf2f(unsigned short h) {
    return __uint_as_float(((unsigned int)h) << 16);
}
static __device__ __forceinline__ void gload_lds16(const void* g, void* s) {
    __builtin_amdgcn_global_load_lds(
        (const __attribute__((address_space(1))) unsigned int*)g,
        (__attribute__((address_space(3))) unsigned int*)s, 16, 0, 0);
}

// ---------------------------------------------------------------------------
// c_norm[k] = sum_d codebook[k][d]^2 (exact f32)
// ---------------------------------------------------------------------------
__global__ __launch_bounds__(256) void cnorm_kernel(const float* __restrict__ cb,
                                                    float* __restrict__ cn) {
    int lane = threadIdx.x & 63;
    int k = blockIdx.x * 4 + (threadIdx.x >> 6);
    float4 v = ((const float4*)(cb + (size_t)k * DD))[lane];
    float s = v.x * v.x + v.y * v.y + v.z * v.z + v.w * v.w;
#pragma unroll
    for (int m = 32; m; m >>= 1) s += __shfl_xor(s, m);
    if (lane == 0) cn[k] = s;
}

// ---------------------------------------------------------------------------
// split-bf16 prep: dst row = [hi | (swap?lo:hi) | (swap?hi:lo)], D2=768
// z2: swap=0 -> [hi|hi|lo];  cb2: swap=1 -> [hi|lo|hi]
// ---------------------------------------------------------------------------
__global__ __launch_bounds__(256) void split_kernel(const float* __restrict__ src,
                                                    unsigned short* __restrict__ dst,
                                                    int swap) {
    int t = blockIdx.x * 256 + threadIdx.x;
    int row = t >> 6, dq = t & 63;
    float4 v = ((const float4*)src)[t];
    unsigned short h[4], lo[4];
    float fv[4] = {v.x, v.y, v.z, v.w};
#pragma unroll
    for (int j = 0; j < 4; ++j) {
        unsigned short hh = f2bf(fv[j]);
        h[j] = hh;
        lo[j] = f2bf(fv[j] - bf2f(hh));
    }
    ushort4 h4 = make_ushort4(h[0], h[1], h[2], h[3]);
    ushort4 l4 = make_ushort4(lo[0], lo[1], lo[2], lo[3]);
    size_t base = (size_t)row * D2 + dq * 4;
    *(ushort4*)&dst[base] = h4;
    *(ushort4*)&dst[base + 256] = swap ? l4 : h4;
    *(ushort4*)&dst[base + 512] = swap ? h4 : l4;
}

// ---------------------------------------------------------------------------
// MFMA argmin GEMM: dist[i,k] = cn[k] - 2*dot(z2_i, cb2_k)  (D_eff = 768)
// 128x128 tile, BK=64, 4 waves, wave = 64x64 (4x4 MFMA 16x16x32 tiles).
// Grid = (B/128) * 2 K-halves.  Emits per-row top-2 (val,idx) per half.
// ---------------------------------------------------------------------------
__global__ __launch_bounds__(256, 2) void
mfma_argmin_kernel(const unsigned short* __restrict__ z2,
                   const unsigned short* __restrict__ cb2,
                   const float* __restrict__ cn,
                   float4* __restrict__ cand) {
    __shared__ unsigned short As[128 * 64];
    __shared__ unsigned short Bs[128 * 64];
    __shared__ float4 red[2][128];

    const int tid = threadIdx.x;
    const int l = tid & 63, w = tid >> 6;
    const int rb = blockIdx.x >> 1, half = blockIdx.x & 1;
    const int row0 = rb * 128;
    const int col0 = half * 2048;
    const int wm = w & 1, wn = w >> 1;
    const int m_off = wm * 64, n_off = wn * 64;
    const int lm = l & 15, lq = l >> 4;

    float best[16];
    int bidx[16];
#pragma unroll
    for (int s = 0; s < 16; ++s) { best[s] = 3.4e38f; bidx[s] = 0; }

    const int g0 = w * 4;
    const int srow = l >> 3;
    const int scol = (l & 7) * 8;

    for (int kc = 0; kc < 2048; kc += 128) {
        f32x4 acc[4][4];
#pragma unroll
        for (int a = 0; a < 4; ++a)
#pragma unroll
            for (int b = 0; b < 4; ++b) acc[a][b] = (f32x4){0.f, 0.f, 0.f, 0.f};

        for (int dc = 0; dc < 12; ++dc) {
            const int dco = dc * 64;
#pragma unroll
            for (int j = 0; j < 4; ++j) {
                const int g = g0 + j;
                const int ar = row0 + g * 8 + srow;
                const int br = col0 + kc + g * 8 + srow;
                gload_lds16(z2 + (size_t)ar * D2 + dco + scol, &As[g * 512]);
                gload_lds16(cb2 + (size_t)br * D2 + dco + scol, &Bs[g * 512]);
            }
            __syncthreads();
#pragma unroll
            for (int ks = 0; ks < 2; ++ks) {
                bf16x8 af[4], bfr[4];
#pragma unroll
                for (int tm = 0; tm < 4; ++tm)
                    af[tm] = *(const bf16x8*)&As[(m_off + tm * 16 + lm) * 64 + ks * 32 + lq * 8];
#pragma unroll
                for (int tn = 0; tn < 4; ++tn)
                    bfr[tn] = *(const bf16x8*)&Bs[(n_off + tn * 16 + lm) * 64 + ks * 32 + lq * 8];
#pragma unroll
                for (int tm = 0; tm < 4; ++tm)
#pragma unroll
                    for (int tn = 0; tn < 4; ++tn)
                        acc[tm][tn] = __builtin_amdgcn_mfma_f32_16x16x32_bf16(
                            af[tm], bfr[tn], acc[tm][tn], 0, 0, 0);
            }
            __syncthreads();
        }
#pragma unroll
        for (int tn = 0; tn < 4; ++tn) {
            const int col = col0 + kc + n_off + tn * 16 + lm;
            const float cnv = cn[col];
#pragma unroll
            for (int tm = 0; tm < 4; ++tm)
#pragma unroll
                for (int r = 0; r < 4; ++r) {
                    float dist = fmaf(-2.0f, acc[tm][tn][r], cnv);
                    int s = tm * 4 + r;
                    if (dist < best[s]) { best[s] = dist; bidx[s] = col; }
                }
        }
    }

    // cross-lane top-2 over the 16 lanes sharing lq
    float v2[16];
    int i2[16];
#pragma unroll
    for (int s = 0; s < 16; ++s) { v2[s] = 3.4e38f; i2[s] = 0x7fffffff; }
#pragma unroll
    for (int m = 1; m < 16; m <<= 1) {
#pragma unroll
        for (int s = 0; s < 16; ++s) {
            float w1 = __shfl_xor(best[s], m); int j1 = __shfl_xor(bidx[s], m);
            float w2 = __shfl_xor(v2[s], m);   int j2 = __shfl_xor(i2[s], m);
            bool b = (w1 < best[s]) || (w1 == best[s] && j1 < bidx[s]);
            if (b) {
                bool c = (best[s] < w2) || (best[s] == w2 && bidx[s] < j2);
                v2[s] = c ? best[s] : w2; i2[s] = c ? bidx[s] : j2;
                best[s] = w1; bidx[s] = j1;
            } else {
                bool c = (w1 < v2[s]) || (w1 == v2[s] && j1 < i2[s]);
                v2[s] = c ? w1 : v2[s]; i2[s] = c ? j1 : i2[s];
            }
        }
    }
    if (lm == 0) {
#pragma unroll
        for (int tm = 0; tm < 4; ++tm)
#pragma unroll
            for (int r = 0; r < 4; ++r) {
                int s = tm * 4 + r;
                int row_local = m_off + tm * 16 + lq * 4 + r;
                red[wn][row_local] =
                    make_float4(best[s], __int_as_float(bidx[s]), v2[s], __int_as_float(i2[s]));
            }
    }
    __syncthreads();
    if (tid < 128) {
        float4 a = red[0][tid], b = red[1][tid];
        float av1 = a.x, av2 = a.z; int ai1 = __float_as_int(a.y), ai2 = __float_as_int(a.w);
        float bv1 = b.x, bv2 = b.z; int bi1 = __float_as_int(b.y), bi2 = __float_as_int(b.w);
        float v1o, v2o; int i1o, i2o;
        bool bb = (bv1 < av1) || (bv1 == av1 && bi1 < ai1);
        if (bb) {
            v1o = bv1; i1o = bi1;
            bool c = (av1 < bv2) || (av1 == bv2 && ai1 < bi2);
            v2o = c ? av1 : bv2; i2o = c ? ai1 : bi2;
        } else {
            v1o = av1; i1o = ai1;
            bool c = (bv1 < av2) || (bv1 == av2 && bi1 < ai2);
            v2o = c ? bv1 : av2; i2o = c ? bi1 : ai2;
        }
        cand[(size_t)half * BB + row0 + tid] =
            make_float4(v1o, __int_as_float(i1o), v2o, __int_as_float(i2o));
    }
}

// ---------------------------------------------------------------------------
// merge the two K-halves; exact f32 re-check when the top-2 gap < TAU
// ---------------------------------------------------------------------------
__global__ __launch_bounds__(256) void merge_refine_kernel(
    const float4* __restrict__ cand, const float* __restrict__ z,
    const float* __restrict__ cb, const float* __restrict__ cn,
    int* __restrict__ idx_i, float* __restrict__ idx_f) {
    int i = blockIdx.x * 256 + threadIdx.x;
    float4 a = cand[i], b = cand[(size_t)BB + i];
    float av1 = a.x, av2 = a.z; int ai1 = __float_as_int(a.y), ai2 = __float_as_int(a.w);
    float bv1 = b.x, bv2 = b.z; int bi1 = __float_as_int(b.y), bi2 = __float_as_int(b.w);
    float v1o, v2o; int i1o, i2o;
    bool bb = (bv1 < av1) || (bv1 == av1 && bi1 < ai1);
    if (bb) {
        v1o = bv1; i1o = bi1;
        bool c = (av1 < bv2) || (av1 == bv2 && ai1 < bi2);
        v2o = c ? av1 : bv2; i2o = c ? ai1 : bi2;
    } else {
        v1o = av1; i1o = ai1;
        bool c = (bv1 < av2) || (bv1 == av2 && bi1 < ai2);
        v2o = c ? bv1 : av2; i2o = c ? bi1 : ai2;
    }
    int kb = i1o;
    if (v2o - v1o < TAU) {
        const float4* zr = (const float4*)(z + (size_t)i * DD);
        const float4* c1 = (const float4*)(cb + (size_t)i1o * DD);
        const float4* c2 = (const float4*)(cb + (size_t)i2o * DD);
        float s1x = 0, s1y = 0, s1z = 0, s1w = 0;
        float s2x = 0, s2y = 0, s2z = 0, s2w = 0;
        for (int j = 0; j < 64; ++j) {
            float4 zv = zr[j], p = c1[j], q = c2[j];
            s1x = fmaf(zv.x, p.x, s1x); s1y = fmaf(zv.y, p.y, s1y);
            s1z = fmaf(zv.z, p.z, s1z); s1w = fmaf(zv.w, p.w, s1w);
            s2x = fmaf(zv.x, q.x, s2x); s2y = fmaf(zv.y, q.y, s2y);
            s2z = fmaf(zv.z, q.z, s2z); s2w = fmaf(zv.w, q.w, s2w);
        }
        float d1 = cn[i1o] - 2.f * ((s1x + s1y) + (s1z + s1w));
        float d2 = cn[i2o] - 2.f * ((s2x + s2y) + (s2z + s2w));
        if (d2 < d1 || (d2 == d1 && i2o < i1o)) kb = i2o;
    }
    idx_i[i] = kb;
    idx_f[i] = (float)kb;
}

// ---------------------------------------------------------------------------
// scatter: 4 rows per block, float4 lanes
// ---------------------------------------------------------------------------
__global__ __launch_bounds__(256) void scatter_kernel(const float* __restrict__ z,
                                                      const float* __restrict__ cb,
                                                      const int* __restrict__ idx_i,
                                                      float* __restrict__ zq,
                                                      float* __restrict__ dw,
                                                      float* __restrict__ counts,
                                                      float* __restrict__ commit_ws) {
    const int w = threadIdx.x >> 6, l = threadIdx.x & 63;
    const int i = blockIdx.x * 4 + w;
    const int k = idx_i[i];
    float4 zv = ((const float4*)z)[(size_t)i * 64 + l];
    float4 cv = ((const float4*)cb)[(size_t)k * 64 + l];
    ((float4*)zq)[(size_t)i * 64 + l] = cv;
    float dx = zv.x - cv.x, dy = zv.y - cv.y, dz = zv.z - cv.z, dq = zv.w - cv.w;
    float s = dx * dx + dy * dy + dz * dz + dq * dq;
#pragma unroll
    for (int m = 32; m; m >>= 1) s += __shfl_xor(s, m);
    float* dp = dw + (size_t)k * DD + l * 4;
    atomicAdd(dp + 0, zv.x); atomicAdd(dp + 1, zv.y);
    atomicAdd(dp + 2, zv.z); atomicAdd(dp + 3, zv.w);
    __shared__ float ls[4];
    if (l == 0) { ls[w] = s; atomicAdd(&counts[k], 1.0f); }
    __syncthreads();
    if (threadIdx.x == 0) atomicAdd(commit_ws, ls[0] + ls[1] + ls[2] + ls[3]);
}

// ---------------------------------------------------------------------------
__global__ __launch_bounds__(256) void cluster_kernel(const float* __restrict__ ema_cs,
                                                      const float* __restrict__ counts,
                                                      float* __restrict__ out_cluster,
                                                      float* __restrict__ n_ws) {
    const int k = blockIdx.x * 256 + threadIdx.x;
    float nc = ema_cs[k] * P_DECAY + counts[k] * (1.0f - P_DECAY);
    out_cluster[k] = nc;
    float s = nc;
#pragma unroll
    for (int m = 32; m; m >>= 1) s += __shfl_xor(s, m);
    __shared__ float ls[4];
    if ((threadIdx.x & 63) == 0) ls[threadIdx.x >> 6] = s;
    __syncthreads();
    if (threadIdx.x == 0) atomicAdd(n_ws, ls[0] + ls[1] + ls[2] + ls[3]);
}

__global__ __launch_bounds__(256) void finalize_kernel(const float* __restrict__ ema_w,
                                                       const float* __restrict__ dw,
                                                       const float* __restrict__ out_cluster,
                                                       const float* __restrict__ n_ws,
                                                       const float* __restrict__ commit_ws,
                                                       float* __restrict__ out_ema_w,
                                                       float* __restrict__ out_codebook,
                                                       float* __restrict__ out_commit) {
    const size_t id = (size_t)blockIdx.x * 256 + threadIdx.x;
    const int k = (int)(id >> 8);
    const float n = *n_ws;
    float nw = ema_w[id] * P_DECAY + dw[id] * (1.0f - P_DECAY);
    out_ema_w[id] = nw;
    float cl = out_cluster[k];
    float csz = (cl + P_EPS) / (n + (float)KC * P_EPS) * n;
    out_codebook[id] = nw / csz;
    if (id == 0) *out_commit = P_BETA * (*commit_ws) / (float)((size_t)BB * DD);
}

// ---------------------------------------------------------------------------
extern "C" void kernel_launch(void* const* d_in, const int* in_sizes, int n_in,
                              void* d_out, int out_size, void* d_ws, size_t ws_size,
                              hipStream_t stream) {
    const float* z      = (const float*)d_in[0];
    const float* cb     = (const float*)d_in[1];
    const float* ema_cs = (const float*)d_in[2];
    const float* ema_w  = (const float*)d_in[3];

    // workspace layout (all 16B-aligned segments)
    float4* cand     = (float4*)d_ws;                          // 2*B float4  (1 MB)
    float* dw        = (float*)(cand + 2 * (size_t)BB);        // K*D         (4 MB)
    float* counts    = dw + (size_t)KC * DD;                   // K
    float* c_norm    = counts + KC;                            // K
    int*   idx_i     = (int*)(c_norm + KC);                    // B
    unsigned short* z2  = (unsigned short*)(idx_i + BB);       // B*768 bf16  (48 MB)
    unsigned short* cb2 = z2 + (size_t)BB * D2;                // K*768 bf16  (6 MB)
    float* commit_ws = (float*)(cb2 + (size_t)KC * D2);        // 1
    float* n_ws      = commit_ws + 1;                          // 1

    float* out        = (float*)d_out;
    float* o_zq       = out;
    float* o_idx      = o_zq + (size_t)BB * DD;
    float* o_commit   = o_idx + BB;
    float* o_codebook = o_commit + 1;
    float* o_cluster  = o_codebook + (size_t)KC * DD;
    float* o_emaw     = o_cluster + KC;

    hipMemsetAsync(dw, 0, (size_t)(KC * DD + KC) * sizeof(float), stream);
    hipMemsetAsync(commit_ws, 0, 2 * sizeof(float), stream);

    cnorm_kernel<<<KC / 4, 256, 0, stream>>>(cb, c_norm);
    split_kernel<<<(BB * 64) / 256, 256, 0, stream>>>(z, z2, 0);
    split_kernel<<<(KC * 64) / 256, 256, 0, stream>>>(cb, cb2, 1);
    mfma_argmin_kernel<<<(BB / 128) * 2, 256, 0, stream>>>(z2, cb2, c_norm, cand);
    merge_refine_kernel<<<BB / 256, 256, 0, stream>>>(cand, z, cb, c_norm, idx_i, o_idx);
    scatter_kernel<<<BB / 4, 256, 0, stream>>>(z, cb, idx_i, o_zq, dw, counts, commit_ws);
    cluster_kernel<<<KC / 256, 256, 0, stream>>>(ema_cs, counts, o_cluster, n_ws);
    finalize_kernel<<<(KC * DD) / 256, 256, 0, stream>>>(ema_w, dw, o_cluster, n_ws,
                                                         commit_ws, o_emaw, o_codebook,
                                                         o_commit);
    (void)in_sizes; (void)n_in; (void)out_size; (void)ws_size;
}

// Round 3
// 580.817 us; speedup vs baseline: 2.4899x; 1.0862x over previous
//
#include <hip/hip_runtime.h>

#define KC 4096
#define DD 256
#define BB 32768
#define D2 768
#define P_BETA 0.25f
#define P_DECAY 0.99f
#define P_EPS 1e-5f
#define TAU 0.1f

typedef __attribute__((ext_vector_type(8))) short bf16x8;
typedef __attribute__((ext_vector_type(4))) float f32x4;

static __device__ __forceinline__ unsigned short f2bf(float f) {
    unsigned int u = __float_as_uint(f);
    unsigned int r = (u + 0x7fffu + ((u >> 16) & 1u)) >> 16;
    return (unsigned short)r;
}
static __device__ __forceinline__ float bf2f(unsigned short h) {
    return __uint_as_float(((unsigned int)h) << 16);
}
static __device__ __forceinline__ void gload_lds16(const void* g, void* s) {
    __builtin_amdgcn_global_load_lds(
        (const __attribute__((address_space(1))) unsigned int*)g,
        (__attribute__((address_space(3))) unsigned int*)s, 16, 0, 0);
}

// ---------------------------------------------------------------------------
// c_norm[k] = sum_d codebook[k][d]^2 (exact f32)
// ---------------------------------------------------------------------------
__global__ __launch_bounds__(256) void cnorm_kernel(const float* __restrict__ cb,
                                                    float* __restrict__ cn) {
    int lane = threadIdx.x & 63;
    int k = blockIdx.x * 4 + (threadIdx.x >> 6);
    float4 v = ((const float4*)(cb + (size_t)k * DD))[lane];
    float s = v.x * v.x + v.y * v.y + v.z * v.z + v.w * v.w;
#pragma unroll
    for (int m = 32; m; m >>= 1) s += __shfl_xor(s, m);
    if (lane == 0) cn[k] = s;
}

// ---------------------------------------------------------------------------
// split-bf16 prep: z2 row = [hi|hi|lo], cb2 row = [hi|lo|hi]  (D2 = 768)
// ---------------------------------------------------------------------------
__global__ __launch_bounds__(256) void split_kernel(const float* __restrict__ src,
                                                    unsigned short* __restrict__ dst,
                                                    int swap) {
    int t = blockIdx.x * 256 + threadIdx.x;
    int row = t >> 6, dq = t & 63;
    float4 v = ((const float4*)src)[t];
    unsigned short h[4], lo[4];
    float fv[4] = {v.x, v.y, v.z, v.w};
#pragma unroll
    for (int j = 0; j < 4; ++j) {
        unsigned short hh = f2bf(fv[j]);
        h[j] = hh;
        lo[j] = f2bf(fv[j] - bf2f(hh));
    }
    ushort4 h4 = make_ushort4(h[0], h[1], h[2], h[3]);
    ushort4 l4 = make_ushort4(lo[0], lo[1], lo[2], lo[3]);
    size_t base = (size_t)row * D2 + dq * 4;
    *(ushort4*)&dst[base] = h4;
    *(ushort4*)&dst[base + 256] = swap ? l4 : h4;
    *(ushort4*)&dst[base + 512] = swap ? h4 : l4;
}

// ---------------------------------------------------------------------------
// MFMA argmin GEMM: dist[i,k] = cn[k] - 2*dot(z2_i, cb2_k)  (D_eff = 768)
// 128x128 tile, BK=64, 4 waves, wave = 64x64 (4x4 MFMA 16x16x32 tiles).
// LDS: XOR-swizzled row-major [row][colblock^(row&7)] -> conflict-free frags.
// Grid XCD-grouped: xcd=b&7, half=xcd>>2  -> each XCD L2 holds one cb2 half.
// Emits per-row top-2 (val,idx) per half.
// ---------------------------------------------------------------------------
__global__ __launch_bounds__(256, 2) void
mfma_argmin_kernel(const unsigned short* __restrict__ z2,
                   const unsigned short* __restrict__ cb2,
                   const float* __restrict__ cn,
                   float4* __restrict__ cand) {
    __shared__ unsigned short As[128 * 64];
    __shared__ unsigned short Bs[128 * 64];
    __shared__ float4 red[2][128];

    const int tid = threadIdx.x;
    const int l = tid & 63, w = tid >> 6;
    const int xcd = blockIdx.x & 7;
    const int half = xcd >> 2;
    const int rb = (blockIdx.x >> 3) * 4 + (xcd & 3);
    const int row0 = rb * 128;
    const int col0 = half * 2048;
    const int wm = w & 1, wn = w >> 1;
    const int m_off = wm * 64, n_off = wn * 64;
    const int lm = l & 15, lq = l >> 4;

    float best[16];
    int bidx[16];
#pragma unroll
    for (int s = 0; s < 16; ++s) { best[s] = 3.4e38f; bidx[s] = 0; }

    const int g0 = w * 4;
    const int srow = l >> 3;
    const int scol = ((l & 7) ^ srow) * 8;  // XOR-swizzled column block

    for (int kc = 0; kc < 2048; kc += 128) {
        f32x4 acc[4][4];
#pragma unroll
        for (int a = 0; a < 4; ++a)
#pragma unroll
            for (int b = 0; b < 4; ++b) acc[a][b] = (f32x4){0.f, 0.f, 0.f, 0.f};

        for (int dc = 0; dc < 12; ++dc) {
            const int dco = dc * 64;
#pragma unroll
            for (int j = 0; j < 4; ++j) {
                const int g = g0 + j;
                const int ar = row0 + g * 8 + srow;
                const int br = col0 + kc + g * 8 + srow;
                gload_lds16(z2 + (size_t)ar * D2 + dco + scol, &As[g * 512]);
                gload_lds16(cb2 + (size_t)br * D2 + dco + scol, &Bs[g * 512]);
            }
            __syncthreads();
#pragma unroll
            for (int ks = 0; ks < 2; ++ks) {
                bf16x8 af[4], bfr[4];
#pragma unroll
                for (int tm = 0; tm < 4; ++tm) {
                    int r = m_off + tm * 16 + lm;
                    af[tm] = *(const bf16x8*)&As[r * 64 + (((ks * 4 + lq) ^ (r & 7)) * 8)];
                }
#pragma unroll
                for (int tn = 0; tn < 4; ++tn) {
                    int r = n_off + tn * 16 + lm;
                    bfr[tn] = *(const bf16x8*)&Bs[r * 64 + (((ks * 4 + lq) ^ (r & 7)) * 8)];
                }
#pragma unroll
                for (int tm = 0; tm < 4; ++tm)
#pragma unroll
                    for (int tn = 0; tn < 4; ++tn)
                        acc[tm][tn] = __builtin_amdgcn_mfma_f32_16x16x32_bf16(
                            af[tm], bfr[tn], acc[tm][tn], 0, 0, 0);
            }
            __syncthreads();
        }
#pragma unroll
        for (int tn = 0; tn < 4; ++tn) {
            const int col = col0 + kc + n_off + tn * 16 + lm;
            const float cnv = cn[col];
#pragma unroll
            for (int tm = 0; tm < 4; ++tm)
#pragma unroll
                for (int r = 0; r < 4; ++r) {
                    float dist = fmaf(-2.0f, acc[tm][tn][r], cnv);
                    int s = tm * 4 + r;
                    if (dist < best[s]) { best[s] = dist; bidx[s] = col; }
                }
        }
    }

    // cross-lane top-2 over the 16 lanes sharing lq
    float v2[16];
    int i2[16];
#pragma unroll
    for (int s = 0; s < 16; ++s) { v2[s] = 3.4e38f; i2[s] = 0x7fffffff; }
#pragma unroll
    for (int m = 1; m < 16; m <<= 1) {
#pragma unroll
        for (int s = 0; s < 16; ++s) {
            float w1 = __shfl_xor(best[s], m); int j1 = __shfl_xor(bidx[s], m);
            float w2 = __shfl_xor(v2[s], m);   int j2 = __shfl_xor(i2[s], m);
            bool b = (w1 < best[s]) || (w1 == best[s] && j1 < bidx[s]);
            if (b) {
                bool c = (best[s] < w2) || (best[s] == w2 && bidx[s] < j2);
                v2[s] = c ? best[s] : w2; i2[s] = c ? bidx[s] : j2;
                best[s] = w1; bidx[s] = j1;
            } else {
                bool c = (w1 < v2[s]) || (w1 == v2[s] && j1 < i2[s]);
                v2[s] = c ? w1 : v2[s]; i2[s] = c ? j1 : i2[s];
            }
        }
    }
    if (lm == 0) {
#pragma unroll
        for (int tm = 0; tm < 4; ++tm)
#pragma unroll
            for (int r = 0; r < 4; ++r) {
                int s = tm * 4 + r;
                int row_local = m_off + tm * 16 + lq * 4 + r;
                red[wn][row_local] =
                    make_float4(best[s], __int_as_float(bidx[s]), v2[s], __int_as_float(i2[s]));
            }
    }
    __syncthreads();
    if (tid < 128) {
        float4 a = red[0][tid], b = red[1][tid];
        float av1 = a.x, av2 = a.z; int ai1 = __float_as_int(a.y), ai2 = __float_as_int(a.w);
        float bv1 = b.x, bv2 = b.z; int bi1 = __float_as_int(b.y), bi2 = __float_as_int(b.w);
        float v1o, v2o; int i1o, i2o;
        bool bb = (bv1 < av1) || (bv1 == av1 && bi1 < ai1);
        if (bb) {
            v1o = bv1; i1o = bi1;
            bool c = (av1 < bv2) || (av1 == bv2 && ai1 < bi2);
            v2o = c ? av1 : bv2; i2o = c ? ai1 : bi2;
        } else {
            v1o = av1; i1o = ai1;
            bool c = (bv1 < av2) || (bv1 == av2 && bi1 < ai2);
            v2o = c ? bv1 : av2; i2o = c ? bi1 : ai2;
        }
        cand[(size_t)half * BB + row0 + tid] =
            make_float4(v1o, __int_as_float(i1o), v2o, __int_as_float(i2o));
    }
}

// ---------------------------------------------------------------------------
// merge the two K-halves; exact f32 re-check when the top-2 gap < TAU
// ---------------------------------------------------------------------------
__global__ __launch_bounds__(256) void merge_refine_kernel(
    const float4* __restrict__ cand, const float* __restrict__ z,
    const float* __restrict__ cb, const float* __restrict__ cn,
    int* __restrict__ idx_i, float* __restrict__ idx_f) {
    int i = blockIdx.x * 256 + threadIdx.x;
    float4 a = cand[i], b = cand[(size_t)BB + i];
    float av1 = a.x, av2 = a.z; int ai1 = __float_as_int(a.y), ai2 = __float_as_int(a.w);
    float bv1 = b.x, bv2 = b.z; int bi1 = __float_as_int(b.y), bi2 = __float_as_int(b.w);
    float v1o, v2o; int i1o, i2o;
    bool bb = (bv1 < av1) || (bv1 == av1 && bi1 < ai1);
    if (bb) {
        v1o = bv1; i1o = bi1;
        bool c = (av1 < bv2) || (av1 == bv2 && ai1 < bi2);
        v2o = c ? av1 : bv2; i2o = c ? ai1 : bi2;
    } else {
        v1o = av1; i1o = ai1;
        bool c = (bv1 < av2) || (bv1 == av2 && bi1 < ai2);
        v2o = c ? bv1 : av2; i2o = c ? bi1 : ai2;
    }
    int kb = i1o;
    if (v2o - v1o < TAU) {
        const float4* zr = (const float4*)(z + (size_t)i * DD);
        const float4* c1 = (const float4*)(cb + (size_t)i1o * DD);
        const float4* c2 = (const float4*)(cb + (size_t)i2o * DD);
        float s1x = 0, s1y = 0, s1z = 0, s1w = 0;
        float s2x = 0, s2y = 0, s2z = 0, s2w = 0;
        for (int j = 0; j < 64; ++j) {
            float4 zv = zr[j], p = c1[j], q = c2[j];
            s1x = fmaf(zv.x, p.x, s1x); s1y = fmaf(zv.y, p.y, s1y);
            s1z = fmaf(zv.z, p.z, s1z); s1w = fmaf(zv.w, p.w, s1w);
            s2x = fmaf(zv.x, q.x, s2x); s2y = fmaf(zv.y, q.y, s2y);
            s2z = fmaf(zv.z, q.z, s2z); s2w = fmaf(zv.w, q.w, s2w);
        }
        float d1 = cn[i1o] - 2.f * ((s1x + s1y) + (s1z + s1w));
        float d2 = cn[i2o] - 2.f * ((s2x + s2y) + (s2z + s2w));
        if (d2 < d1 || (d2 == d1 && i2o < i1o)) kb = i2o;
    }
    idx_i[i] = kb;
    idx_f[i] = (float)kb;
}

// ---------------------------------------------------------------------------
// scatter: 4 rows per block; commit partial per block (NO global atomic)
// ---------------------------------------------------------------------------
__global__ __launch_bounds__(256) void scatter_kernel(const float* __restrict__ z,
                                                      const float* __restrict__ cb,
                                                      const int* __restrict__ idx_i,
                                                      float* __restrict__ zq,
                                                      float* __restrict__ dw,
                                                      float* __restrict__ counts,
                                                      float* __restrict__ commit_parts) {
    const int w = threadIdx.x >> 6, l = threadIdx.x & 63;
    const int i = blockIdx.x * 4 + w;
    const int k = idx_i[i];
    float4 zv = ((const float4*)z)[(size_t)i * 64 + l];
    float4 cv = ((const float4*)cb)[(size_t)k * 64 + l];
    ((float4*)zq)[(size_t)i * 64 + l] = cv;
    float dx = zv.x - cv.x, dy = zv.y - cv.y, dz = zv.z - cv.z, dq = zv.w - cv.w;
    float s = dx * dx + dy * dy + dz * dz + dq * dq;
#pragma unroll
    for (int m = 32; m; m >>= 1) s += __shfl_xor(s, m);
    float* dp = dw + (size_t)k * DD + l * 4;
    atomicAdd(dp + 0, zv.x); atomicAdd(dp + 1, zv.y);
    atomicAdd(dp + 2, zv.z); atomicAdd(dp + 3, zv.w);
    __shared__ float ls[4];
    if (l == 0) { ls[w] = s; atomicAdd(&counts[k], 1.0f); }
    __syncthreads();
    if (threadIdx.x == 0) commit_parts[blockIdx.x] = ls[0] + ls[1] + ls[2] + ls[3];
}

// ---------------------------------------------------------------------------
// commit_reduce: sum 8192 block partials -> o_commit (single block)
// ---------------------------------------------------------------------------
__global__ __launch_bounds__(256) void commit_reduce_kernel(
    const float* __restrict__ commit_parts, float* __restrict__ out_commit) {
    float s = 0.f;
    for (int j = threadIdx.x; j < BB / 4; j += 256) s += commit_parts[j];
#pragma unroll
    for (int m = 32; m; m >>= 1) s += __shfl_xor(s, m);
    __shared__ float ls[4];
    if ((threadIdx.x & 63) == 0) ls[threadIdx.x >> 6] = s;
    __syncthreads();
    if (threadIdx.x == 0)
        *out_commit = P_BETA * (ls[0] + ls[1] + ls[2] + ls[3]) / (float)((size_t)BB * DD);
}

// ---------------------------------------------------------------------------
__global__ __launch_bounds__(256) void cluster_kernel(const float* __restrict__ ema_cs,
                                                      const float* __restrict__ counts,
                                                      float* __restrict__ out_cluster,
                                                      float* __restrict__ n_ws) {
    const int k = blockIdx.x * 256 + threadIdx.x;
    float nc = ema_cs[k] * P_DECAY + counts[k] * (1.0f - P_DECAY);
    out_cluster[k] = nc;
    float s = nc;
#pragma unroll
    for (int m = 32; m; m >>= 1) s += __shfl_xor(s, m);
    __shared__ float ls[4];
    if ((threadIdx.x & 63) == 0) ls[threadIdx.x >> 6] = s;
    __syncthreads();
    if (threadIdx.x == 0) atomicAdd(n_ws, ls[0] + ls[1] + ls[2] + ls[3]);
}

__global__ __launch_bounds__(256) void finalize_kernel(const float* __restrict__ ema_w,
                                                       const float* __restrict__ dw,
                                                       const float* __restrict__ out_cluster,
                                                       const float* __restrict__ n_ws,
                                                       float* __restrict__ out_ema_w,
                                                       float* __restrict__ out_codebook) {
    const size_t id = (size_t)blockIdx.x * 256 + threadIdx.x;
    const int k = (int)(id >> 8);
    const float n = *n_ws;
    float nw = ema_w[id] * P_DECAY + dw[id] * (1.0f - P_DECAY);
    out_ema_w[id] = nw;
    float cl = out_cluster[k];
    float csz = (cl + P_EPS) / (n + (float)KC * P_EPS) * n;
    out_codebook[id] = nw / csz;
}

// ---------------------------------------------------------------------------
extern "C" void kernel_launch(void* const* d_in, const int* in_sizes, int n_in,
                              void* d_out, int out_size, void* d_ws, size_t ws_size,
                              hipStream_t stream) {
    const float* z      = (const float*)d_in[0];
    const float* cb     = (const float*)d_in[1];
    const float* ema_cs = (const float*)d_in[2];
    const float* ema_w  = (const float*)d_in[3];

    // workspace layout (all 16B-aligned segments)
    float4* cand     = (float4*)d_ws;                          // 2*B float4  (1 MB)
    float* dw        = (float*)(cand + 2 * (size_t)BB);        // K*D         (4 MB)
    float* counts    = dw + (size_t)KC * DD;                   // K
    float* c_norm    = counts + KC;                            // K
    int*   idx_i     = (int*)(c_norm + KC);                    // B
    unsigned short* z2  = (unsigned short*)(idx_i + BB);       // B*768 bf16  (48 MB)
    unsigned short* cb2 = z2 + (size_t)BB * D2;                // K*768 bf16  (6 MB)
    float* commit_parts = (float*)(cb2 + (size_t)KC * D2);     // B/4
    float* n_ws      = commit_parts + BB / 4;                  // 1

    float* out        = (float*)d_out;
    float* o_zq       = out;
    float* o_idx      = o_zq + (size_t)BB * DD;
    float* o_commit   = o_idx + BB;
    float* o_codebook = o_commit + 1;
    float* o_cluster  = o_codebook + (size_t)KC * DD;
    float* o_emaw     = o_cluster + KC;

    hipMemsetAsync(dw, 0, (size_t)(KC * DD + KC) * sizeof(float), stream);
    hipMemsetAsync(n_ws, 0, sizeof(float), stream);

    cnorm_kernel<<<KC / 4, 256, 0, stream>>>(cb, c_norm);
    split_kernel<<<(BB * 64) / 256, 256, 0, stream>>>(z, z2, 0);
    split_kernel<<<(KC * 64) / 256, 256, 0, stream>>>(cb, cb2, 1);
    mfma_argmin_kernel<<<(BB / 128) * 2, 256, 0, stream>>>(z2, cb2, c_norm, cand);
    merge_refine_kernel<<<BB / 256, 256, 0, stream>>>(cand, z, cb, c_norm, idx_i, o_idx);
    scatter_kernel<<<BB / 4, 256, 0, stream>>>(z, cb, idx_i, o_zq, dw, counts, commit_parts);
    commit_reduce_kernel<<<1, 256, 0, stream>>>(commit_parts, o_commit);
    cluster_kernel<<<KC / 256, 256, 0, stream>>>(ema_cs, counts, o_cluster, n_ws);
    finalize_kernel<<<(KC * DD) / 256, 256, 0, stream>>>(ema_w, dw, o_cluster, n_ws,
                                                         o_emaw, o_codebook);
    (void)in_sizes; (void)n_in; (void)out_size; (void)ws_size;
}

// Round 4
// 416.295 us; speedup vs baseline: 3.4739x; 1.3952x over previous
//
#include <hip/hip_runtime.h>

#define KC 4096
#define DD 256
#define BB 32768
#define P_BETA 0.25f
#define P_DECAY 0.99f
#define P_EPS 1e-5f
#define TAU 0.5f

typedef __attribute__((ext_vector_type(8))) short bf16x8;
typedef __attribute__((ext_vector_type(4))) float f32x4;

static __device__ __forceinline__ unsigned short f2bf(float f) {
    unsigned int u = __float_as_uint(f);
    unsigned int r = (u + 0x7fffu + ((u >> 16) & 1u)) >> 16;
    return (unsigned short)r;
}
static __device__ __forceinline__ void gload_lds16(const void* g, void* s) {
    __builtin_amdgcn_global_load_lds(
        (const __attribute__((address_space(1))) unsigned int*)g,
        (__attribute__((address_space(3))) unsigned int*)s, 16, 0, 0);
}

// ---------------------------------------------------------------------------
// convert z -> bf16 (row-major, same layout)
// ---------------------------------------------------------------------------
__global__ __launch_bounds__(256) void convert_z_kernel(const float* __restrict__ src,
                                                        unsigned short* __restrict__ dst) {
    int t = blockIdx.x * 256 + threadIdx.x;
    float4 v = ((const float4*)src)[t];
    *(ushort4*)&dst[(size_t)t * 4] =
        make_ushort4(f2bf(v.x), f2bf(v.y), f2bf(v.z), f2bf(v.w));
}

// ---------------------------------------------------------------------------
// convert cb -> bf16, fused exact-f32 c_norm (wave per row: 4 rows/block)
// ---------------------------------------------------------------------------
__global__ __launch_bounds__(256) void convert_cb_kernel(const float* __restrict__ cb,
                                                         unsigned short* __restrict__ dst,
                                                         float* __restrict__ cn) {
    int t = blockIdx.x * 256 + threadIdx.x;
    int lane = threadIdx.x & 63;
    int row = blockIdx.x * 4 + (threadIdx.x >> 6);
    float4 v = ((const float4*)cb)[t];
    *(ushort4*)&dst[(size_t)t * 4] =
        make_ushort4(f2bf(v.x), f2bf(v.y), f2bf(v.z), f2bf(v.w));
    float s = v.x * v.x + v.y * v.y + v.z * v.z + v.w * v.w;
#pragma unroll
    for (int m = 32; m; m >>= 1) s += __shfl_xor(s, m);
    if (lane == 0) cn[row] = s;
}

// ---------------------------------------------------------------------------
// MFMA argmin: dist[i,k] = cn[k] - 2*dot(z_i, c_k), plain bf16 screening.
// 128x128 tile, D=256.  A-tile (z rows, 64 KB) staged to LDS ONCE;
// B-tile staged 16 KB per (kc,dc) step.  LDS = 80 KB -> 2 blocks/CU.
// XOR swizzles on both tiles -> conflict-free frag reads (2-way max).
// Emits per-row top-2 (val,idx) per K-half; exact refine happens downstream.
// ---------------------------------------------------------------------------
__global__ __launch_bounds__(256, 2) void
mfma_argmin_kernel(const unsigned short* __restrict__ zb,
                   const unsigned short* __restrict__ cbb,
                   const float* __restrict__ cn,
                   float4* __restrict__ cand) {
    __shared__ unsigned short As[128 * 256];  // 64 KB, persistent z-tile
    __shared__ unsigned short Bs[128 * 64];   // 16 KB, per-step cb-tile

    const int tid = threadIdx.x;
    const int l = tid & 63, w = tid >> 6;
    const int xcd = blockIdx.x & 7;
    const int half = xcd >> 2;
    const int rb = (blockIdx.x >> 3) * 4 + (xcd & 3);
    const int row0 = rb * 128;
    const int col0 = half * 2048;
    const int wm = w & 1, wn = w >> 1;
    const int m_off = wm * 64, n_off = wn * 64;
    const int lm = l & 15, lq = l >> 4;

    // ---- stage As once: wave w covers rows i*8 + w*2 + (l>>5), 16 iters ----
    {
        const int lrow = w * 2 + (l >> 5);           // local row within 8-group
        const int coff = ((l & 31) ^ lrow) * 8;      // XOR-swizzled 16B block
#pragma unroll
        for (int i = 0; i < 16; ++i) {
            gload_lds16(zb + (size_t)(row0 + i * 8 + lrow) * DD + coff,
                        &As[(i * 8 + w * 2) * 256]);
        }
    }

    const int srow = l >> 3;
    const int scol = ((l & 7) ^ srow) * 8;
    const int g0 = w * 4;

    float best[16];
    int bidx[16];
#pragma unroll
    for (int s = 0; s < 16; ++s) { best[s] = 3.4e38f; bidx[s] = 0; }

    for (int kc = 0; kc < 2048; kc += 128) {
        f32x4 acc[4][4];
#pragma unroll
        for (int a = 0; a < 4; ++a)
#pragma unroll
            for (int b = 0; b < 4; ++b) acc[a][b] = (f32x4){0.f, 0.f, 0.f, 0.f};

        for (int dc = 0; dc < 4; ++dc) {
#pragma unroll
            for (int j = 0; j < 4; ++j) {
                const int g = g0 + j;
                const int br = col0 + kc + g * 8 + srow;
                gload_lds16(cbb + (size_t)br * DD + dc * 64 + scol, &Bs[g * 512]);
            }
            __syncthreads();
#pragma unroll
            for (int ks = 0; ks < 2; ++ks) {
                bf16x8 af[4], bfr[4];
                const int cbi = dc * 8 + ks * 4 + lq;  // 16B-block column index
#pragma unroll
                for (int tm = 0; tm < 4; ++tm) {
                    int r = m_off + tm * 16 + lm;
                    af[tm] = *(const bf16x8*)&As[r * 256 + ((cbi ^ (r & 7)) * 8)];
                }
#pragma unroll
                for (int tn = 0; tn < 4; ++tn) {
                    int r = n_off + tn * 16 + lm;
                    bfr[tn] = *(const bf16x8*)&Bs[r * 64 + (((ks * 4 + lq) ^ (r & 7)) * 8)];
                }
#pragma unroll
                for (int tm = 0; tm < 4; ++tm)
#pragma unroll
                    for (int tn = 0; tn < 4; ++tn)
                        acc[tm][tn] = __builtin_amdgcn_mfma_f32_16x16x32_bf16(
                            af[tm], bfr[tn], acc[tm][tn], 0, 0, 0);
            }
            __syncthreads();
        }
#pragma unroll
        for (int tn = 0; tn < 4; ++tn) {
            const int col = col0 + kc + n_off + tn * 16 + lm;
            const float cnv = cn[col];
#pragma unroll
            for (int tm = 0; tm < 4; ++tm)
#pragma unroll
                for (int r = 0; r < 4; ++r) {
                    float dist = fmaf(-2.0f, acc[tm][tn][r], cnv);
                    int s = tm * 4 + r;
                    if (dist < best[s]) { best[s] = dist; bidx[s] = col; }
                }
        }
    }

    // cross-lane top-2 over the 16 lanes sharing lq
    float v2[16];
    int i2[16];
#pragma unroll
    for (int s = 0; s < 16; ++s) { v2[s] = 3.4e38f; i2[s] = 0x7fffffff; }
#pragma unroll
    for (int m = 1; m < 16; m <<= 1) {
#pragma unroll
        for (int s = 0; s < 16; ++s) {
            float w1 = __shfl_xor(best[s], m); int j1 = __shfl_xor(bidx[s], m);
            float w2 = __shfl_xor(v2[s], m);   int j2 = __shfl_xor(i2[s], m);
            bool b = (w1 < best[s]) || (w1 == best[s] && j1 < bidx[s]);
            if (b) {
                bool c = (best[s] < w2) || (best[s] == w2 && bidx[s] < j2);
                v2[s] = c ? best[s] : w2; i2[s] = c ? bidx[s] : j2;
                best[s] = w1; bidx[s] = j1;
            } else {
                bool c = (w1 < v2[s]) || (w1 == v2[s] && j1 < i2[s]);
                v2[s] = c ? w1 : v2[s]; i2[s] = c ? j1 : i2[s];
            }
        }
    }

    // cross-wave merge through LDS (alias red into As; all As reads are done)
    float4* red = (float4*)As;  // red[wn*128 + row_local]
    if (lm == 0) {
#pragma unroll
        for (int tm = 0; tm < 4; ++tm)
#pragma unroll
            for (int r = 0; r < 4; ++r) {
                int s = tm * 4 + r;
                int row_local = m_off + tm * 16 + lq * 4 + r;
                red[wn * 128 + row_local] =
                    make_float4(best[s], __int_as_float(bidx[s]), v2[s], __int_as_float(i2[s]));
            }
    }
    __syncthreads();
    if (tid < 128) {
        float4 a = red[tid], b = red[128 + tid];
        float av1 = a.x, av2 = a.z; int ai1 = __float_as_int(a.y), ai2 = __float_as_int(a.w);
        float bv1 = b.x, bv2 = b.z; int bi1 = __float_as_int(b.y), bi2 = __float_as_int(b.w);
        float v1o, v2o; int i1o, i2o;
        bool bb = (bv1 < av1) || (bv1 == av1 && bi1 < ai1);
        if (bb) {
            v1o = bv1; i1o = bi1;
            bool c = (av1 < bv2) || (av1 == bv2 && ai1 < bi2);
            v2o = c ? av1 : bv2; i2o = c ? ai1 : bi2;
        } else {
            v1o = av1; i1o = ai1;
            bool c = (bv1 < av2) || (bv1 == av2 && bi1 < ai2);
            v2o = c ? bv1 : av2; i2o = c ? bi1 : ai2;
        }
        cand[(size_t)half * BB + row0 + tid] =
            make_float4(v1o, __int_as_float(i1o), v2o, __int_as_float(i2o));
    }
}

// ---------------------------------------------------------------------------
// merge the two K-halves; exact f32 re-check when the top-2 gap < TAU
// ---------------------------------------------------------------------------
__global__ __launch_bounds__(256) void merge_refine_kernel(
    const float4* __restrict__ cand, const float* __restrict__ z,
    const float* __restrict__ cb, const float* __restrict__ cn,
    int* __restrict__ idx_i, float* __restrict__ idx_f) {
    int i = blockIdx.x * 256 + threadIdx.x;
    float4 a = cand[i], b = cand[(size_t)BB + i];
    float av1 = a.x, av2 = a.z; int ai1 = __float_as_int(a.y), ai2 = __float_as_int(a.w);
    float bv1 = b.x, bv2 = b.z; int bi1 = __float_as_int(b.y), bi2 = __float_as_int(b.w);
    float v1o, v2o; int i1o, i2o;
    bool bb = (bv1 < av1) || (bv1 == av1 && bi1 < ai1);
    if (bb) {
        v1o = bv1; i1o = bi1;
        bool c = (av1 < bv2) || (av1 == bv2 && ai1 < bi2);
        v2o = c ? av1 : bv2; i2o = c ? ai1 : bi2;
    } else {
        v1o = av1; i1o = ai1;
        bool c = (bv1 < av2) || (bv1 == av2 && bi1 < ai2);
        v2o = c ? bv1 : av2; i2o = c ? bi1 : ai2;
    }
    int kb = i1o;
    if (v2o - v1o < TAU) {
        const float4* zr = (const float4*)(z + (size_t)i * DD);
        const float4* c1 = (const float4*)(cb + (size_t)i1o * DD);
        const float4* c2 = (const float4*)(cb + (size_t)i2o * DD);
        float s1x = 0, s1y = 0, s1z = 0, s1w = 0;
        float s2x = 0, s2y = 0, s2z = 0, s2w = 0;
        for (int j = 0; j < 64; ++j) {
            float4 zv = zr[j], p = c1[j], q = c2[j];
            s1x = fmaf(zv.x, p.x, s1x); s1y = fmaf(zv.y, p.y, s1y);
            s1z = fmaf(zv.z, p.z, s1z); s1w = fmaf(zv.w, p.w, s1w);
            s2x = fmaf(zv.x, q.x, s2x); s2y = fmaf(zv.y, q.y, s2y);
            s2z = fmaf(zv.z, q.z, s2z); s2w = fmaf(zv.w, q.w, s2w);
        }
        float d1 = cn[i1o] - 2.f * ((s1x + s1y) + (s1z + s1w));
        float d2 = cn[i2o] - 2.f * ((s2x + s2y) + (s2z + s2w));
        if (d2 < d1 || (d2 == d1 && i2o < i1o)) kb = i2o;
    }
    idx_i[i] = kb;
    idx_f[i] = (float)kb;
}

// ---------------------------------------------------------------------------
// scatter: 4 rows per block; commit partial per block
// ---------------------------------------------------------------------------
__global__ __launch_bounds__(256) void scatter_kernel(const float* __restrict__ z,
                                                      const float* __restrict__ cb,
                                                      const int* __restrict__ idx_i,
                                                      float* __restrict__ zq,
                                                      float* __restrict__ dw,
                                                      float* __restrict__ counts,
                                                      float* __restrict__ commit_parts) {
    const int w = threadIdx.x >> 6, l = threadIdx.x & 63;
    const int i = blockIdx.x * 4 + w;
    const int k = idx_i[i];
    float4 zv = ((const float4*)z)[(size_t)i * 64 + l];
    float4 cv = ((const float4*)cb)[(size_t)k * 64 + l];
    ((float4*)zq)[(size_t)i * 64 + l] = cv;
    float dx = zv.x - cv.x, dy = zv.y - cv.y, dz = zv.z - cv.z, dq = zv.w - cv.w;
    float s = dx * dx + dy * dy + dz * dz + dq * dq;
#pragma unroll
    for (int m = 32; m; m >>= 1) s += __shfl_xor(s, m);
    float* dp = dw + (size_t)k * DD + l * 4;
    atomicAdd(dp + 0, zv.x); atomicAdd(dp + 1, zv.y);
    atomicAdd(dp + 2, zv.z); atomicAdd(dp + 3, zv.w);
    __shared__ float ls[4];
    if (l == 0) { ls[w] = s; atomicAdd(&counts[k], 1.0f); }
    __syncthreads();
    if (threadIdx.x == 0) commit_parts[blockIdx.x] = ls[0] + ls[1] + ls[2] + ls[3];
}

// ---------------------------------------------------------------------------
// single block: commit reduce + new_cluster + n   (no atomics needed)
// ---------------------------------------------------------------------------
__global__ __launch_bounds__(256) void cluster_commit_kernel(
    const float* __restrict__ ema_cs, const float* __restrict__ counts,
    const float* __restrict__ commit_parts, float* __restrict__ out_cluster,
    float* __restrict__ n_ws, float* __restrict__ out_commit) {
    const int t = threadIdx.x;
    float cs = 0.f;
    for (int j = t; j < BB / 4; j += 256) cs += commit_parts[j];
    float ns = 0.f;
    for (int j = t; j < KC; j += 256) {
        float nc = ema_cs[j] * P_DECAY + counts[j] * (1.0f - P_DECAY);
        out_cluster[j] = nc;
        ns += nc;
    }
#pragma unroll
    for (int m = 32; m; m >>= 1) { cs += __shfl_xor(cs, m); ns += __shfl_xor(ns, m); }
    __shared__ float lc[4], ln[4];
    if ((t & 63) == 0) { lc[t >> 6] = cs; ln[t >> 6] = ns; }
    __syncthreads();
    if (t == 0) {
        *out_commit = P_BETA * (lc[0] + lc[1] + lc[2] + lc[3]) / (float)((size_t)BB * DD);
        *n_ws = ln[0] + ln[1] + ln[2] + ln[3];
    }
}

// ---------------------------------------------------------------------------
__global__ __launch_bounds__(256) void finalize_kernel(const float* __restrict__ ema_w,
                                                       const float* __restrict__ dw,
                                                       const float* __restrict__ out_cluster,
                                                       const float* __restrict__ n_ws,
                                                       float* __restrict__ out_ema_w,
                                                       float* __restrict__ out_codebook) {
    const size_t id = (size_t)blockIdx.x * 256 + threadIdx.x;
    const int k = (int)(id >> 8);
    const float n = *n_ws;
    float nw = ema_w[id] * P_DECAY + dw[id] * (1.0f - P_DECAY);
    out_ema_w[id] = nw;
    float cl = out_cluster[k];
    float csz = (cl + P_EPS) / (n + (float)KC * P_EPS) * n;
    out_codebook[id] = nw / csz;
}

// ---------------------------------------------------------------------------
extern "C" void kernel_launch(void* const* d_in, const int* in_sizes, int n_in,
                              void* d_out, int out_size, void* d_ws, size_t ws_size,
                              hipStream_t stream) {
    const float* z      = (const float*)d_in[0];
    const float* cb     = (const float*)d_in[1];
    const float* ema_cs = (const float*)d_in[2];
    const float* ema_w  = (const float*)d_in[3];

    // workspace layout (16B-aligned segments)
    float4* cand     = (float4*)d_ws;                          // 2*B float4 (1 MB)
    float* dw        = (float*)(cand + 2 * (size_t)BB);        // K*D (4 MB)
    float* counts    = dw + (size_t)KC * DD;                   // K
    float* c_norm    = counts + KC;                            // K
    int*   idx_i     = (int*)(c_norm + KC);                    // B
    unsigned short* zb  = (unsigned short*)(idx_i + BB);       // B*256 bf16 (16 MB)
    unsigned short* cbb = zb + (size_t)BB * DD;                // K*256 bf16 (2 MB)
    float* commit_parts = (float*)(cbb + (size_t)KC * DD);     // B/4
    float* n_ws      = commit_parts + BB / 4;                  // 1

    float* out        = (float*)d_out;
    float* o_zq       = out;
    float* o_idx      = o_zq + (size_t)BB * DD;
    float* o_commit   = o_idx + BB;
    float* o_codebook = o_commit + 1;
    float* o_cluster  = o_codebook + (size_t)KC * DD;
    float* o_emaw     = o_cluster + KC;

    hipMemsetAsync(dw, 0, (size_t)(KC * DD + KC) * sizeof(float), stream);

    convert_z_kernel<<<(BB * DD / 4) / 256, 256, 0, stream>>>(z, zb);
    convert_cb_kernel<<<KC / 4, 256, 0, stream>>>(cb, cbb, c_norm);
    mfma_argmin_kernel<<<(BB / 128) * 2, 256, 0, stream>>>(zb, cbb, c_norm, cand);
    merge_refine_kernel<<<BB / 256, 256, 0, stream>>>(cand, z, cb, c_norm, idx_i, o_idx);
    scatter_kernel<<<BB / 4, 256, 0, stream>>>(z, cb, idx_i, o_zq, dw, counts, commit_parts);
    cluster_commit_kernel<<<1, 256, 0, stream>>>(ema_cs, counts, commit_parts,
                                                 o_cluster, n_ws, o_commit);
    finalize_kernel<<<(KC * DD) / 256, 256, 0, stream>>>(ema_w, dw, o_cluster, n_ws,
                                                         o_emaw, o_codebook);
    (void)in_sizes; (void)n_in; (void)out_size; (void)ws_size;
}